// Round 5
// baseline (441.482 us; speedup 1.0000x reference)
//
#include <hip/hip_runtime.h>
#include <hip/hip_bf16.h>
#include <stdint.h>

// ---------------------------------------------------------------------------
// AttentionBlock: y = Attn(RoPE(x@wq^T), RoPE(x@wk^T), x@wv^T) @ wo^T
// B=2 T=2048 D=2048 H=32 HD=64. FP32 in/out, bf16 MFMA internal (2% budget).
//
// r4 -> r5 (r4: 413us; flash ~120us est., gemm_qkv 131us at m97 plateau):
//  - flash v4: NO barriers, NO K/V LDS. V pre-transposed in global (vt) so
//    both K (A-frag) and V^T (B-frag) fragments load directly from global
//    (L1/L2); only the per-wave P C->A round-trip stays in LDS.
//  - 1-D flash grid bid=gx*64+bh: the 8 blocks sharing a (b,h) K/V column
//    are congruent mod 8 -> same XCD under round-robin -> L2 reuse.
//  - rope folds log2(e) into q-scale; softmax uses exp2f (bare v_exp_f32).
//  - buffers: vt aliases xb (x dead after QKV gemm), Y aliases vb (V dead
//    after transpose). ws unchanged: 92.3 MB path A / 75.5 MB path B.
// ---------------------------------------------------------------------------

typedef __bf16 bf16_t;
typedef __bf16 bf16x4 __attribute__((ext_vector_type(4)));
typedef __bf16 bf16x8 __attribute__((ext_vector_type(8)));
typedef float  f32x4  __attribute__((ext_vector_type(4)));

constexpr int B_ = 2, T_ = 2048, D_ = 2048, H_ = 32, HD_ = 64;
constexpr int M_ = B_ * T_;   // 4096 token rows

// async global->LDS, 16B per lane; LDS dest = wave-uniform base + lane*16
__device__ __forceinline__ void async_copy16(const bf16_t* g, bf16_t* l) {
  __builtin_amdgcn_global_load_lds(
      (const __attribute__((address_space(1))) void*)g,
      (__attribute__((address_space(3))) void*)l, 16, 0, 0);
}

// ---------------------------------------------------------------------------
// f32 -> bf16 cast, 4 elements/thread.
// ---------------------------------------------------------------------------
__global__ __launch_bounds__(256) void cast_f32_bf16(
    const float* __restrict__ src, bf16_t* __restrict__ dst, int n4)
{
  const int i = blockIdx.x * 256 + threadIdx.x;
  if (i >= n4) return;
  const float4 v = ((const float4*)src)[i];
  bf16x4 o;
  o[0] = (bf16_t)v.x; o[1] = (bf16_t)v.y; o[2] = (bf16_t)v.z; o[3] = (bf16_t)v.w;
  ((bf16x4*)dst)[i] = o;
}

// ---------------------------------------------------------------------------
// GEMM: C[M][N] = A[M][K] . B[N][K]^T — m97 structure.
// ---------------------------------------------------------------------------
template <typename OutT>
__global__ __launch_bounds__(256, 2) void gemm_bt(
    const bf16_t* __restrict__ A, const bf16_t* __restrict__ B,
    OutT* __restrict__ C, int M, int N, int K)
{
  __shared__ __attribute__((aligned(16))) bf16_t As[128 * 32];
  __shared__ __attribute__((aligned(16))) bf16_t Bs[128 * 32];

  const int tid    = threadIdx.x;
  const int w      = tid >> 6;
  const int l      = tid & 63;
  const int quad   = l >> 4;
  const int lane16 = l & 15;
  const int bm0 = blockIdx.x * 128;
  const int bn0 = blockIdx.y * 128;
  const int wm  = (w >> 1) * 64;
  const int wn  = (w & 1) * 64;
  const int srow = l >> 2;
  const int scol = (l & 3) * 8;

  const bf16_t* Ag = A + (size_t)bm0 * K;
  const bf16_t* Bg = B + (size_t)bn0 * K;

  f32x4 acc[4][4] = {};

  for (int kk = 0; kk < K; kk += 32) {
    __syncthreads();
#pragma unroll
    for (int s0 = 0; s0 < 2; ++s0) {
      const int s = w + s0 * 4;
      async_copy16(Ag + (size_t)(s * 16 + srow) * K + kk + scol, &As[s * 512]);
      async_copy16(Bg + (size_t)(s * 16 + srow) * K + kk + scol, &Bs[s * 512]);
    }
    __syncthreads();

    bf16x8 af[4], bfr[4];
#pragma unroll
    for (int i = 0; i < 4; ++i)
      af[i] = *(const bf16x8*)&As[(wm + i * 16 + lane16) * 32 + quad * 8];
#pragma unroll
    for (int j = 0; j < 4; ++j)
      bfr[j] = *(const bf16x8*)&Bs[(wn + j * 16 + lane16) * 32 + quad * 8];
#pragma unroll
    for (int i = 0; i < 4; ++i)
#pragma unroll
      for (int j = 0; j < 4; ++j)
        acc[i][j] = __builtin_amdgcn_mfma_f32_16x16x32_bf16(af[i], bfr[j],
                                                            acc[i][j], 0, 0, 0);
  }

#pragma unroll
  for (int i = 0; i < 4; ++i) {
#pragma unroll
    for (int r = 0; r < 4; ++r) {
      const size_t row = (size_t)(bm0 + wm + i * 16 + quad * 4 + r);
#pragma unroll
      for (int j = 0; j < 4; ++j) {
        const int col = bn0 + wn + j * 16 + lane16;
        C[row * N + col] = (OutT)acc[i][j][r];
      }
    }
  }
}

// ---------------------------------------------------------------------------
// Merged-QKV GEMM: B = concat(wq|wk|wv) [6144][2048]; epilogue base-selects
// into compact q/k/v buffers (each [M][2048]). Grid (M/128, 48).
// ---------------------------------------------------------------------------
__global__ __launch_bounds__(256, 2) void gemm_qkv(
    const bf16_t* __restrict__ A, const bf16_t* __restrict__ B,
    bf16_t* __restrict__ Cq, bf16_t* __restrict__ Ck, bf16_t* __restrict__ Cv,
    int M, int K)
{
  __shared__ __attribute__((aligned(16))) bf16_t As[128 * 32];
  __shared__ __attribute__((aligned(16))) bf16_t Bs[128 * 32];

  const int tid    = threadIdx.x;
  const int w      = tid >> 6;
  const int l      = tid & 63;
  const int quad   = l >> 4;
  const int lane16 = l & 15;
  const int bm0 = blockIdx.x * 128;
  const int bn0 = blockIdx.y * 128;
  const int wm  = (w >> 1) * 64;
  const int wn  = (w & 1) * 64;
  const int srow = l >> 2;
  const int scol = (l & 3) * 8;

  const bf16_t* Ag = A + (size_t)bm0 * K;
  const bf16_t* Bg = B + (size_t)bn0 * K;

  f32x4 acc[4][4] = {};

  for (int kk = 0; kk < K; kk += 32) {
    __syncthreads();
#pragma unroll
    for (int s0 = 0; s0 < 2; ++s0) {
      const int s = w + s0 * 4;
      async_copy16(Ag + (size_t)(s * 16 + srow) * K + kk + scol, &As[s * 512]);
      async_copy16(Bg + (size_t)(s * 16 + srow) * K + kk + scol, &Bs[s * 512]);
    }
    __syncthreads();

    bf16x8 af[4], bfr[4];
#pragma unroll
    for (int i = 0; i < 4; ++i)
      af[i] = *(const bf16x8*)&As[(wm + i * 16 + lane16) * 32 + quad * 8];
#pragma unroll
    for (int j = 0; j < 4; ++j)
      bfr[j] = *(const bf16x8*)&Bs[(wn + j * 16 + lane16) * 32 + quad * 8];
#pragma unroll
    for (int i = 0; i < 4; ++i)
#pragma unroll
      for (int j = 0; j < 4; ++j)
        acc[i][j] = __builtin_amdgcn_mfma_f32_16x16x32_bf16(af[i], bfr[j],
                                                            acc[i][j], 0, 0, 0);
  }

  bf16_t* Cb = (bn0 < 2048) ? Cq : (bn0 < 4096) ? Ck : Cv;
  const int cb0 = (bn0 & 2047) + wn;
#pragma unroll
  for (int i = 0; i < 4; ++i) {
#pragma unroll
    for (int r = 0; r < 4; ++r) {
      const size_t row = (size_t)(bm0 + wm + i * 16 + quad * 4 + r);
#pragma unroll
      for (int j = 0; j < 4; ++j)
        Cb[row * 2048 + cb0 + j * 16 + lane16] = (bf16_t)acc[i][j][r];
    }
  }
}

// ---------------------------------------------------------------------------
// RoPE in-place on bf16 q,k; folds (1/sqrt(64))*log2(e) into q so softmax
// can use exp2 directly (v_exp_f32 is a native exp2).
// ---------------------------------------------------------------------------
__global__ __launch_bounds__(256) void rope_kernel(
    bf16_t* __restrict__ q, bf16_t* __restrict__ k,
    const float* __restrict__ cosb, const float* __restrict__ sinb, int npair)
{
  const int idx = blockIdx.x * 256 + threadIdx.x;
  if (idx >= npair) return;
  const int p = idx & 31;
  const int t = (idx >> 10) & (T_ - 1);
  const float c = cosb[t * 32 + p];
  const float s = sinb[t * 32 + p];
  const size_t off = (size_t)idx * 2;
  const float qs = 0.125f * 1.44269504f;   // score-scale * log2(e)

  const float qr = (float)q[off], qi = (float)q[off + 1];
  q[off]     = (bf16_t)((qr * c - qi * s) * qs);
  q[off + 1] = (bf16_t)((qr * s + qi * c) * qs);

  const float kr = (float)k[off], ki = (float)k[off + 1];
  k[off]     = (bf16_t)(kr * c - ki * s);
  k[off + 1] = (bf16_t)(kr * s + ki * c);
}

// ---------------------------------------------------------------------------
// V transpose: vb[(b*T+t)*2048 + h*64+d] -> vt[(b*32+h)*64*2048 + d*2048 + t]
// Per block: one (b,h) x 64-token tile. LDS 64x72 (b128-aligned reads).
// ---------------------------------------------------------------------------
__global__ __launch_bounds__(256) void transpose_v(
    const bf16_t* __restrict__ vb, bf16_t* __restrict__ vt)
{
  __shared__ __attribute__((aligned(16))) bf16_t Lt[64 * 72];
  const int tid = threadIdx.x;
  const int bh  = blockIdx.y;          // b*32+h
  const int tt  = blockIdx.x;          // token tile
  const int b   = bh >> 5, h = bh & 31;

  const int tl = tid >> 3;             // 0..31
  const int j8 = (tid & 7) * 8;        // octet

#pragma unroll
  for (int rep = 0; rep < 2; ++rep) {
    const int t_loc = rep * 32 + tl;
    const bf16x8 v = *(const bf16x8*)(vb + ((size_t)b * T_ + tt * 64 + t_loc) * 2048 +
                                      h * 64 + j8);
#pragma unroll
    for (int i = 0; i < 8; ++i)
      Lt[(j8 + i) * 72 + t_loc] = v[i];
  }
  __syncthreads();
#pragma unroll
  for (int rep = 0; rep < 2; ++rep) {
    const int d = rep * 32 + tl;
    const bf16x8 v = *(const bf16x8*)&Lt[d * 72 + j8];
    *(bf16x8*)(vt + ((size_t)bh * 64 + d) * 2048 + tt * 64 + j8) = v;
  }
}

// ---------------------------------------------------------------------------
// Flash attention v4 (causal, exp2 softmax, paired q-groups, NO barriers).
// Block bid = gx*64 + bh (gx 0..7): handles q-groups {gx*128, (15-gx)*128},
// 4 waves x 32 rows per group. 64-key steps. K A-frags and V^T B-frags load
// DIRECTLY from global (coalesced 16B, L1-shared across waves, L2-shared
// across the 8 same-bh blocks on one XCD). Only P's C->A layout round-trip
// uses LDS (per-wave, padded, no barrier).
// ---------------------------------------------------------------------------
__global__ __launch_bounds__(256, 2) void flash_attn(
    const bf16_t* __restrict__ Q, const bf16_t* __restrict__ K,
    const bf16_t* __restrict__ Vt, bf16_t* __restrict__ Y)
{
  __shared__ __attribute__((aligned(16))) bf16_t Pt[4 * 2 * 16 * 68];

  const int tid    = threadIdx.x;
  const int w      = tid >> 6;
  const int l      = tid & 63;
  const int quad   = l >> 4;
  const int lane16 = l & 15;
  const int bid = blockIdx.x;           // 512 = 8 gx * 64 bh
  const int gx  = bid >> 6;             // 0..7
  const int bh  = bid & 63;             // same-bh blocks are congruent mod 8
  const int b   = bh >> 5, h = bh & 31;
  int qa[2];
  qa[0] = gx * 128 + w * 32;
  qa[1] = (15 - gx) * 128 + w * 32;
  const size_t rs = (size_t)H_ * HD_;   // 2048

  const bf16_t* Qb  = Q + ((size_t)b * T_) * rs + h * HD_;
  const bf16_t* Kb  = K + ((size_t)b * T_) * rs + h * HD_;
  const bf16_t* Vtb = Vt + (size_t)bh * HD_ * T_;   // [dim][t]

  // Q B-frags: [grp][tile][chunk]  n=lane16(q-row), k=quad*8+j(dim)
  bf16x8 qf[2][2][2];
#pragma unroll
  for (int g = 0; g < 2; ++g)
#pragma unroll
    for (int t = 0; t < 2; ++t)
#pragma unroll
      for (int c = 0; c < 2; ++c)
        qf[g][t][c] = *(const bf16x8*)(Qb + (size_t)(qa[g] + t * 16 + lane16) * rs +
                                       c * 32 + quad * 8);

  f32x4 o[2][2][4] = {};       // [grp][tile][dim-tile]
  float lsum[2][2] = {};       // [grp][tile]

  bf16_t* const PtW = Pt + w * (2 * 16 * 68);
  const int nsteps = (15 - gx) * 2 + 2;

  for (int it = 0; it < nsteps; ++it) {
    const int k0 = it * 64;

    // ---- K A-frags [c][kt]: m=key=kt*16+lane16, k=dim=c*32+quad*8+j ----
    // ---- V B-frags [c][n]:  n=dim=n*16+lane16,  k=key=c*32+quad*8+j ----
    bf16x8 kf[2][4], vf[2][4];
#pragma unroll
    for (int c = 0; c < 2; ++c) {
#pragma unroll
      for (int kt = 0; kt < 4; ++kt)
        kf[c][kt] = *(const bf16x8*)(Kb + (size_t)(k0 + kt * 16 + lane16) * rs +
                                     c * 32 + quad * 8);
#pragma unroll
      for (int n = 0; n < 4; ++n)
        vf[c][n] = *(const bf16x8*)(Vtb + (size_t)(n * 16 + lane16) * T_ +
                                    k0 + c * 32 + quad * 8);
    }

#pragma unroll
    for (int g = 0; g < 2; ++g) {
      if (k0 > qa[g] + 31) continue;     // group fully masked (wave-uniform)

      // ---- S^T = K.Q^T : rows=key, cols=q ----
      f32x4 stx[4][2] = {};
#pragma unroll
      for (int c = 0; c < 2; ++c) {
#pragma unroll
        for (int kt = 0; kt < 4; ++kt) {
          stx[kt][0] = __builtin_amdgcn_mfma_f32_16x16x32_bf16(kf[c][kt], qf[g][0][c],
                                                               stx[kt][0], 0, 0, 0);
          stx[kt][1] = __builtin_amdgcn_mfma_f32_16x16x32_bf16(kf[c][kt], qf[g][1][c],
                                                               stx[kt][1], 0, 0, 0);
        }
      }

      // ---- softmax numerator: p = exp2(s); log2e folded into q scale ----
#pragma unroll
      for (int t = 0; t < 2; ++t) {
        const int qbase = qa[g] + t * 16;
#pragma unroll
        for (int kt = 0; kt < 4; ++kt) {
          const int kbase = k0 + kt * 16 + quad * 4;
          const bool anymask = (k0 + kt * 16 + 15) > qbase;   // wave-uniform
          float p[4];
#pragma unroll
          for (int r = 0; r < 4; ++r) {
            float s = stx[kt][t][r];
            if (anymask) s = (kbase + r > qbase + lane16) ? -1e30f : s;
            p[r] = exp2f(s);
          }
          lsum[g][t] += (p[0] + p[1]) + (p[2] + p[3]);
          bf16x4 pv;
          pv[0] = (bf16_t)p[0]; pv[1] = (bf16_t)p[1];
          pv[2] = (bf16_t)p[2]; pv[3] = (bf16_t)p[3];
          *(bf16x4*)&PtW[(t * 16 + lane16) * 68 + kt * 16 + quad * 4] = pv;
        }
      }

      // ---- O += P.V ----
#pragma unroll
      for (int c = 0; c < 2; ++c) {
        const bf16x8 pf0 = *(const bf16x8*)&PtW[(0 * 16 + lane16) * 68 + c * 32 + quad * 8];
        const bf16x8 pf1 = *(const bf16x8*)&PtW[(1 * 16 + lane16) * 68 + c * 32 + quad * 8];
#pragma unroll
        for (int n = 0; n < 4; ++n) {
          o[g][0][n] = __builtin_amdgcn_mfma_f32_16x16x32_bf16(pf0, vf[c][n], o[g][0][n], 0, 0, 0);
          o[g][1][n] = __builtin_amdgcn_mfma_f32_16x16x32_bf16(pf1, vf[c][n], o[g][1][n], 0, 0, 0);
        }
      }
    }
  }

  // ---- epilogue ----
  bf16_t* Yb = Y + ((size_t)b * T_) * rs + h * HD_;
#pragma unroll
  for (int g = 0; g < 2; ++g) {
#pragma unroll
    for (int t = 0; t < 2; ++t) {
      float lt = lsum[g][t];
      lt += __shfl_xor(lt, 16);
      lt += __shfl_xor(lt, 32);
#pragma unroll
      for (int r = 0; r < 4; ++r) {
        const float linv = 1.0f / __shfl(lt, quad * 4 + r);
        const size_t row = (size_t)(qa[g] + t * 16 + quad * 4 + r);
#pragma unroll
        for (int n = 0; n < 4; ++n)
          Yb[row * rs + n * 16 + lane16] = (bf16_t)(o[g][t][n][r] * linv);
      }
    }
  }
}

// ---------------------------------------------------------------------------
extern "C" void kernel_launch(void* const* d_in, const int* in_sizes, int n_in,
                              void* d_out, int out_size, void* d_ws, size_t ws_size,
                              hipStream_t stream)
{
  (void)in_sizes; (void)n_in; (void)out_size;
  const float* x  = (const float*)d_in[0];
  const float* fc = (const float*)d_in[1];
  const float* fs = (const float*)d_in[2];
  const float* wq = (const float*)d_in[3];
  const float* wk = (const float*)d_in[4];
  const float* wv = (const float*)d_in[5];
  const float* wo = (const float*)d_in[6];
  float* out = (float*)d_out;

  const size_t nx = (size_t)M_ * D_;        // 8.39M
  const size_t nw = (size_t)D_ * D_;        // 4.19M
  const dim3 blk(256);
  const int nx4 = (int)(nx / 4), nw4 = (int)(nw / 4);
  const dim3 gg(M_ / 128, D_ / 128);        // 32 x 16
  const dim3 gt(T_ / 64, B_ * H_);          // transpose grid

  if (ws_size >= (3 * nw + 4 * nx) * sizeof(bf16_t)) {
    // ---- Path A: merged QKV gemm (92.3 MB ws) ----
    // wb3[3nw] | xb[nx] | qb[nx] | kb[nx] | vb[nx]; vt:=xb (x dead after
    // gemm_qkv), Y:=vb (V dead after transpose).
    bf16_t* ws  = (bf16_t*)d_ws;
    bf16_t* wb3 = ws;
    bf16_t* xb  = ws + 3 * nw;
    bf16_t* qb  = xb + nx;
    bf16_t* kb  = qb + nx;
    bf16_t* vb  = kb + nx;
    bf16_t* vt  = xb;
    bf16_t* yb  = vb;

    cast_f32_bf16<<<dim3(nx4 / 256), blk, 0, stream>>>(x, xb, nx4);
    cast_f32_bf16<<<dim3(nw4 / 256), blk, 0, stream>>>(wq, wb3, nw4);
    cast_f32_bf16<<<dim3(nw4 / 256), blk, 0, stream>>>(wk, wb3 + nw, nw4);
    cast_f32_bf16<<<dim3(nw4 / 256), blk, 0, stream>>>(wv, wb3 + 2 * nw, nw4);

    gemm_qkv<<<dim3(M_ / 128, 48), blk, 0, stream>>>(xb, wb3, qb, kb, vb, M_, D_);

    rope_kernel<<<dim3((B_ * T_ * H_ * 32) / 256), blk, 0, stream>>>(
        qb, kb, fc, fs, B_ * T_ * H_ * 32);
    transpose_v<<<gt, blk, 0, stream>>>(vb, vt);
    flash_attn<<<dim3(8 * B_ * H_), blk, 0, stream>>>(qb, kb, vt, yb);

    cast_f32_bf16<<<dim3(nw4 / 256), blk, 0, stream>>>(wo, wb3, nw4);
    gemm_bt<float><<<gg, blk, 0, stream>>>(yb, wb3, out, M_, D_, D_);
  } else {
    // ---- Path B: serial 3-gemm fallback (75.5 MB ws) ----
    bf16_t* ws = (bf16_t*)d_ws;
    bf16_t* wb = ws;
    bf16_t* xb = ws + nw;
    bf16_t* qb = xb + nx;
    bf16_t* kb = qb + nx;
    bf16_t* vb = kb + nx;
    bf16_t* vt = xb;
    bf16_t* yb = vb;

    cast_f32_bf16<<<dim3(nx4 / 256), blk, 0, stream>>>(x, xb, nx4);
    cast_f32_bf16<<<dim3(nw4 / 256), blk, 0, stream>>>(wq, wb, nw4);
    gemm_bt<bf16_t><<<gg, blk, 0, stream>>>(xb, wb, qb, M_, D_, D_);
    cast_f32_bf16<<<dim3(nw4 / 256), blk, 0, stream>>>(wk, wb, nw4);
    gemm_bt<bf16_t><<<gg, blk, 0, stream>>>(xb, wb, kb, M_, D_, D_);
    cast_f32_bf16<<<dim3(nw4 / 256), blk, 0, stream>>>(wv, wb, nw4);
    gemm_bt<bf16_t><<<gg, blk, 0, stream>>>(xb, wb, vb, M_, D_, D_);

    rope_kernel<<<dim3((B_ * T_ * H_ * 32) / 256), blk, 0, stream>>>(
        qb, kb, fc, fs, B_ * T_ * H_ * 32);
    transpose_v<<<gt, blk, 0, stream>>>(vb, vt);
    flash_attn<<<dim3(8 * B_ * H_), blk, 0, stream>>>(qb, kb, vt, yb);

    cast_f32_bf16<<<dim3(nw4 / 256), blk, 0, stream>>>(wo, wb, nw4);
    gemm_bt<float><<<gg, blk, 0, stream>>>(yb, wb, out, M_, D_, D_);
  }
}

// Round 6
// 429.655 us; speedup vs baseline: 1.0275x; 1.0275x over previous
//
#include <hip/hip_runtime.h>
#include <hip/hip_bf16.h>
#include <stdint.h>

// ---------------------------------------------------------------------------
// AttentionBlock: y = Attn(RoPE(x@wq^T), RoPE(x@wk^T), x@wv^T) @ wo^T
// B=2 T=2048 D=2048 H=32 HD=64. FP32 in/out, bf16 MFMA internal (2% budget).
//
// r5 -> r6 (r5 regressed 413->441: global-direct flash frags were latency-
// bound; LDS staging + prefetch was better):
//  - flash: REVERT to r4's LDS-staged structure (fragment-granule K, XOR-
//    swizzled transposed V, paired q-groups, register prefetch).
//  - RoPE FUSED into flash: Q rotated at frag load (pairs are in-lane, cos/
//    sin is one float4), K rotated at prefetch before LDS write. Deletes the
//    rope dispatch and a 67MB q/k round-trip. exp2 + log2e fold kept (r5-
//    validated numerics).
//  - transpose_v deleted.
// ---------------------------------------------------------------------------

typedef __bf16 bf16_t;
typedef __bf16 bf16x4 __attribute__((ext_vector_type(4)));
typedef __bf16 bf16x8 __attribute__((ext_vector_type(8)));
typedef float  f32x4  __attribute__((ext_vector_type(4)));

constexpr int B_ = 2, T_ = 2048, D_ = 2048, H_ = 32, HD_ = 64;
constexpr int M_ = B_ * T_;   // 4096 token rows

// async global->LDS, 16B per lane; LDS dest = wave-uniform base + lane*16
__device__ __forceinline__ void async_copy16(const bf16_t* g, bf16_t* l) {
  __builtin_amdgcn_global_load_lds(
      (const __attribute__((address_space(1))) void*)g,
      (__attribute__((address_space(3))) void*)l, 16, 0, 0);
}

// rotate 4 interleaved pairs held in one bf16x8; cos/sin from fc/fs[base_pair..+3]
__device__ __forceinline__ bf16x8 rope8(bf16x8 v, const float* __restrict__ fc,
                                        const float* __restrict__ fs,
                                        int base_pair, float scale) {
  const float4 c4 = *(const float4*)(fc + base_pair);
  const float4 s4 = *(const float4*)(fs + base_pair);
  const float c[4] = {c4.x, c4.y, c4.z, c4.w};
  const float s[4] = {s4.x, s4.y, s4.z, s4.w};
  bf16x8 o;
#pragma unroll
  for (int m = 0; m < 4; ++m) {
    const float xr = (float)v[2 * m], xi = (float)v[2 * m + 1];
    o[2 * m]     = (bf16_t)((xr * c[m] - xi * s[m]) * scale);
    o[2 * m + 1] = (bf16_t)((xr * s[m] + xi * c[m]) * scale);
  }
  return o;
}

// ---------------------------------------------------------------------------
// f32 -> bf16 cast, 4 elements/thread.
// ---------------------------------------------------------------------------
__global__ __launch_bounds__(256) void cast_f32_bf16(
    const float* __restrict__ src, bf16_t* __restrict__ dst, int n4)
{
  const int i = blockIdx.x * 256 + threadIdx.x;
  if (i >= n4) return;
  const float4 v = ((const float4*)src)[i];
  bf16x4 o;
  o[0] = (bf16_t)v.x; o[1] = (bf16_t)v.y; o[2] = (bf16_t)v.z; o[3] = (bf16_t)v.w;
  ((bf16x4*)dst)[i] = o;
}

// ---------------------------------------------------------------------------
// GEMM: C[M][N] = A[M][K] . B[N][K]^T — m97 structure.
// ---------------------------------------------------------------------------
template <typename OutT>
__global__ __launch_bounds__(256, 2) void gemm_bt(
    const bf16_t* __restrict__ A, const bf16_t* __restrict__ B,
    OutT* __restrict__ C, int M, int N, int K)
{
  __shared__ __attribute__((aligned(16))) bf16_t As[128 * 32];
  __shared__ __attribute__((aligned(16))) bf16_t Bs[128 * 32];

  const int tid    = threadIdx.x;
  const int w      = tid >> 6;
  const int l      = tid & 63;
  const int quad   = l >> 4;
  const int lane16 = l & 15;
  const int bm0 = blockIdx.x * 128;
  const int bn0 = blockIdx.y * 128;
  const int wm  = (w >> 1) * 64;
  const int wn  = (w & 1) * 64;
  const int srow = l >> 2;
  const int scol = (l & 3) * 8;

  const bf16_t* Ag = A + (size_t)bm0 * K;
  const bf16_t* Bg = B + (size_t)bn0 * K;

  f32x4 acc[4][4] = {};

  for (int kk = 0; kk < K; kk += 32) {
    __syncthreads();
#pragma unroll
    for (int s0 = 0; s0 < 2; ++s0) {
      const int s = w + s0 * 4;
      async_copy16(Ag + (size_t)(s * 16 + srow) * K + kk + scol, &As[s * 512]);
      async_copy16(Bg + (size_t)(s * 16 + srow) * K + kk + scol, &Bs[s * 512]);
    }
    __syncthreads();

    bf16x8 af[4], bfr[4];
#pragma unroll
    for (int i = 0; i < 4; ++i)
      af[i] = *(const bf16x8*)&As[(wm + i * 16 + lane16) * 32 + quad * 8];
#pragma unroll
    for (int j = 0; j < 4; ++j)
      bfr[j] = *(const bf16x8*)&Bs[(wn + j * 16 + lane16) * 32 + quad * 8];
#pragma unroll
    for (int i = 0; i < 4; ++i)
#pragma unroll
      for (int j = 0; j < 4; ++j)
        acc[i][j] = __builtin_amdgcn_mfma_f32_16x16x32_bf16(af[i], bfr[j],
                                                            acc[i][j], 0, 0, 0);
  }

#pragma unroll
  for (int i = 0; i < 4; ++i) {
#pragma unroll
    for (int r = 0; r < 4; ++r) {
      const size_t row = (size_t)(bm0 + wm + i * 16 + quad * 4 + r);
#pragma unroll
      for (int j = 0; j < 4; ++j) {
        const int col = bn0 + wn + j * 16 + lane16;
        C[row * N + col] = (OutT)acc[i][j][r];
      }
    }
  }
}

// ---------------------------------------------------------------------------
// Merged-QKV GEMM: B = concat(wq|wk|wv) [6144][2048]; epilogue base-selects
// into compact q/k/v buffers (each [M][2048]). Grid (M/128, 48).
// ---------------------------------------------------------------------------
__global__ __launch_bounds__(256, 2) void gemm_qkv(
    const bf16_t* __restrict__ A, const bf16_t* __restrict__ B,
    bf16_t* __restrict__ Cq, bf16_t* __restrict__ Ck, bf16_t* __restrict__ Cv,
    int M, int K)
{
  __shared__ __attribute__((aligned(16))) bf16_t As[128 * 32];
  __shared__ __attribute__((aligned(16))) bf16_t Bs[128 * 32];

  const int tid    = threadIdx.x;
  const int w      = tid >> 6;
  const int l      = tid & 63;
  const int quad   = l >> 4;
  const int lane16 = l & 15;
  const int bm0 = blockIdx.x * 128;
  const int bn0 = blockIdx.y * 128;
  const int wm  = (w >> 1) * 64;
  const int wn  = (w & 1) * 64;
  const int srow = l >> 2;
  const int scol = (l & 3) * 8;

  const bf16_t* Ag = A + (size_t)bm0 * K;
  const bf16_t* Bg = B + (size_t)bn0 * K;

  f32x4 acc[4][4] = {};

  for (int kk = 0; kk < K; kk += 32) {
    __syncthreads();
#pragma unroll
    for (int s0 = 0; s0 < 2; ++s0) {
      const int s = w + s0 * 4;
      async_copy16(Ag + (size_t)(s * 16 + srow) * K + kk + scol, &As[s * 512]);
      async_copy16(Bg + (size_t)(s * 16 + srow) * K + kk + scol, &Bs[s * 512]);
    }
    __syncthreads();

    bf16x8 af[4], bfr[4];
#pragma unroll
    for (int i = 0; i < 4; ++i)
      af[i] = *(const bf16x8*)&As[(wm + i * 16 + lane16) * 32 + quad * 8];
#pragma unroll
    for (int j = 0; j < 4; ++j)
      bfr[j] = *(const bf16x8*)&Bs[(wn + j * 16 + lane16) * 32 + quad * 8];
#pragma unroll
    for (int i = 0; i < 4; ++i)
#pragma unroll
      for (int j = 0; j < 4; ++j)
        acc[i][j] = __builtin_amdgcn_mfma_f32_16x16x32_bf16(af[i], bfr[j],
                                                            acc[i][j], 0, 0, 0);
  }

  bf16_t* Cb = (bn0 < 2048) ? Cq : (bn0 < 4096) ? Ck : Cv;
  const int cb0 = (bn0 & 2047) + wn;
#pragma unroll
  for (int i = 0; i < 4; ++i) {
#pragma unroll
    for (int r = 0; r < 4; ++r) {
      const size_t row = (size_t)(bm0 + wm + i * 16 + quad * 4 + r);
#pragma unroll
      for (int j = 0; j < 4; ++j)
        Cb[row * 2048 + cb0 + j * 16 + lane16] = (bf16_t)acc[i][j][r];
    }
  }
}

// ---------------------------------------------------------------------------
// Flash attention v5 (r4 structure + fused RoPE + exp2 softmax).
// Block (gx, bh): q-groups {gx*128, (15-gx)*128}, 4 waves x 32 rows/group.
// 64-key steps, K/V staged in LDS (fragment-granule K, XOR-swizzled V^T),
// register prefetch of next step. RoPE applied to Q at frag load and to K
// at prefetch (cos/sin are contiguous float4 per 8-dim octet).
// q-scale carries 0.125*log2(e) so softmax is exp2f (bare v_exp_f32).
// ---------------------------------------------------------------------------
__global__ __launch_bounds__(256, 2) void flash_attn(
    const bf16_t* __restrict__ Q, const bf16_t* __restrict__ K,
    const bf16_t* __restrict__ V, bf16_t* __restrict__ Y,
    const float* __restrict__ fc, const float* __restrict__ fs)
{
  __shared__ __attribute__((aligned(16))) bf16_t Kf[4096];
  __shared__ __attribute__((aligned(16))) bf16_t Vf[4096];
  __shared__ __attribute__((aligned(16))) bf16_t Pt[4 * 2 * 16 * 68];

  const int tid    = threadIdx.x;
  const int w      = tid >> 6;
  const int l      = tid & 63;
  const int quad   = l >> 4;
  const int lane16 = l & 15;
  const int bh = blockIdx.y;
  const int b  = bh >> 5;
  const int h  = bh & 31;
  const int gx = blockIdx.x;            // 0..7
  int qa[2];
  qa[0] = gx * 128 + w * 32;            // light group
  qa[1] = (15 - gx) * 128 + w * 32;     // heavy group
  const size_t rs = (size_t)H_ * HD_;

  const bf16_t* Qb = Q + ((size_t)b * T_) * rs + h * HD_;
  const bf16_t* Kb = K + ((size_t)b * T_) * rs + h * HD_;
  const bf16_t* Vb = V + ((size_t)b * T_) * rs + h * HD_;
  const float qs = 0.125f * 1.44269504f;   // score-scale * log2(e)

  // Q B-frags (RoPE'd): n=lane16(q-row), k=quad*8+j(dim); pairs in-lane
  bf16x8 qf[2][2][2];
#pragma unroll
  for (int g = 0; g < 2; ++g)
#pragma unroll
    for (int t = 0; t < 2; ++t)
#pragma unroll
      for (int c = 0; c < 2; ++c) {
        const int row = qa[g] + t * 16 + lane16;
        bf16x8 raw = *(const bf16x8*)(Qb + (size_t)row * rs + c * 32 + quad * 8);
        qf[g][t][c] = rope8(raw, fc, fs, row * 32 + c * 16 + quad * 4, qs);
      }

  f32x4 o[2][2][4] = {};       // [grp][tile][dim-tile]
  float lsum[2][2] = {};       // [grp][tile]

  // staging assignment: thread = (key-offset, dim-octet)
  const int koff = tid >> 3;
  const int oct  = tid & 7;
  const int d0   = oct * 8;
  const int kc = oct >> 2, kq = oct & 3;
  const int nV = oct >> 1, base16 = (oct & 1) * 8;

  bf16_t* const PtW = Pt + w * (2 * 16 * 68);

  const int nsteps = (15 - gx) * 2 + 2;   // keys [0, (15-gx)*128 + 128)

  // prefetch step 0 (K RoPE'd at load; pair base = key*32 + oct*4)
  bf16x8 kr[2], vr[2];
#pragma unroll
  for (int hf = 0; hf < 2; ++hf) {
    const int key = hf * 32 + koff;
    bf16x8 raw = *(const bf16x8*)(Kb + (size_t)key * rs + d0);
    kr[hf] = rope8(raw, fc, fs, key * 32 + oct * 4, 1.0f);
    vr[hf] = *(const bf16x8*)(Vb + (size_t)key * rs + d0);
  }

  for (int it = 0; it < nsteps; ++it) {
    const int k0 = it * 64;
    __syncthreads();
#pragma unroll
    for (int hf = 0; hf < 2; ++hf) {
      const int key = hf * 32 + koff;
      const int gK = ((kc * 4 + (key >> 4)) * 16 + (key & 15)) * 4 + kq;
      *(bf16x8*)&Kf[gK * 8] = kr[hf];
      const int cV = key >> 5, qV = (key >> 3) & 3, jV = key & 7;
#pragma unroll
      for (int i = 0; i < 8; ++i) {
        const int gv = ((cV * 4 + nV) * 16 + base16 + i) * 4 + qV;
        Vf[(gv ^ oct) * 8 + jV] = vr[hf][i];
      }
    }
    __syncthreads();
    if (it + 1 < nsteps) {
      const int k0n = k0 + 64;
#pragma unroll
      for (int hf = 0; hf < 2; ++hf) {
        const int key = k0n + hf * 32 + koff;
        bf16x8 raw = *(const bf16x8*)(Kb + (size_t)key * rs + d0);
        kr[hf] = rope8(raw, fc, fs, key * 32 + oct * 4, 1.0f);
        vr[hf] = *(const bf16x8*)(Vb + (size_t)key * rs + d0);
      }
    }

#pragma unroll
    for (int g = 0; g < 2; ++g) {
      if (k0 > qa[g] + 31) continue;       // group fully masked (wave-uniform)

      // ---- S^T = K.Q^T ----
      f32x4 stx[4][2] = {};
#pragma unroll
      for (int c = 0; c < 2; ++c) {
#pragma unroll
        for (int kt = 0; kt < 4; ++kt) {
          const bf16x8 kfr =
              *(const bf16x8*)&Kf[(((c * 4 + kt) * 16 + lane16) * 4 + quad) * 8];
          stx[kt][0] = __builtin_amdgcn_mfma_f32_16x16x32_bf16(kfr, qf[g][0][c],
                                                               stx[kt][0], 0, 0, 0);
          stx[kt][1] = __builtin_amdgcn_mfma_f32_16x16x32_bf16(kfr, qf[g][1][c],
                                                               stx[kt][1], 0, 0, 0);
        }
      }

      // ---- softmax numerator: p = exp2(s) ----
#pragma unroll
      for (int t = 0; t < 2; ++t) {
        const int qbase = qa[g] + t * 16;
#pragma unroll
        for (int kt = 0; kt < 4; ++kt) {
          const int kbase = k0 + kt * 16 + quad * 4;
          const bool anymask = (k0 + kt * 16 + 15) > qbase;   // wave-uniform
          float p[4];
#pragma unroll
          for (int r = 0; r < 4; ++r) {
            float s = stx[kt][t][r];
            if (anymask) s = (kbase + r > qbase + lane16) ? -1e30f : s;
            p[r] = exp2f(s);
          }
          lsum[g][t] += (p[0] + p[1]) + (p[2] + p[3]);
          bf16x4 pv;
          pv[0] = (bf16_t)p[0]; pv[1] = (bf16_t)p[1];
          pv[2] = (bf16_t)p[2]; pv[3] = (bf16_t)p[3];
          *(bf16x4*)&PtW[(t * 16 + lane16) * 68 + kt * 16 + quad * 4] = pv;
        }
      }

      // ---- O += P.V ----
#pragma unroll
      for (int c = 0; c < 2; ++c) {
        const bf16x8 pf0 = *(const bf16x8*)&PtW[(0 * 16 + lane16) * 68 + c * 32 + quad * 8];
        const bf16x8 pf1 = *(const bf16x8*)&PtW[(1 * 16 + lane16) * 68 + c * 32 + quad * 8];
#pragma unroll
        for (int n = 0; n < 4; ++n) {
          const int gv = ((c * 4 + n) * 16 + lane16) * 4 + quad;
          const int swz = n * 2 + (lane16 >> 3);
          const bf16x8 vfr = *(const bf16x8*)&Vf[(gv ^ swz) * 8];
          o[g][0][n] = __builtin_amdgcn_mfma_f32_16x16x32_bf16(pf0, vfr, o[g][0][n], 0, 0, 0);
          o[g][1][n] = __builtin_amdgcn_mfma_f32_16x16x32_bf16(pf1, vfr, o[g][1][n], 0, 0, 0);
        }
      }
    }
  }

  // ---- epilogue ----
  bf16_t* Yb = Y + ((size_t)b * T_) * rs + h * HD_;
#pragma unroll
  for (int g = 0; g < 2; ++g) {
#pragma unroll
    for (int t = 0; t < 2; ++t) {
      float lt = lsum[g][t];
      lt += __shfl_xor(lt, 16);
      lt += __shfl_xor(lt, 32);
#pragma unroll
      for (int r = 0; r < 4; ++r) {
        const float linv = 1.0f / __shfl(lt, quad * 4 + r);
        const size_t row = (size_t)(qa[g] + t * 16 + quad * 4 + r);
#pragma unroll
        for (int n = 0; n < 4; ++n)
          Yb[row * rs + n * 16 + lane16] = (bf16_t)(o[g][t][n][r] * linv);
      }
    }
  }
}

// ---------------------------------------------------------------------------
extern "C" void kernel_launch(void* const* d_in, const int* in_sizes, int n_in,
                              void* d_out, int out_size, void* d_ws, size_t ws_size,
                              hipStream_t stream)
{
  (void)in_sizes; (void)n_in; (void)out_size;
  const float* x  = (const float*)d_in[0];
  const float* fc = (const float*)d_in[1];
  const float* fs = (const float*)d_in[2];
  const float* wq = (const float*)d_in[3];
  const float* wk = (const float*)d_in[4];
  const float* wv = (const float*)d_in[5];
  const float* wo = (const float*)d_in[6];
  float* out = (float*)d_out;

  const size_t nx = (size_t)M_ * D_;        // 8.39M
  const size_t nw = (size_t)D_ * D_;        // 4.19M
  const dim3 blk(256);
  const int nx4 = (int)(nx / 4), nw4 = (int)(nw / 4);
  const dim3 gg(M_ / 128, D_ / 128);        // 32 x 16

  if (ws_size >= (3 * nw + 4 * nx) * sizeof(bf16_t)) {
    // ---- Path A: merged QKV gemm (92.3 MB ws) ----
    // wb3[3nw] | xb[nx] | qb[nx] | kb[nx] | vb[nx]; yb aliases xb.
    bf16_t* ws  = (bf16_t*)d_ws;
    bf16_t* wb3 = ws;
    bf16_t* xb  = ws + 3 * nw;
    bf16_t* qb  = xb + nx;
    bf16_t* kb  = qb + nx;
    bf16_t* vb  = kb + nx;
    bf16_t* yb  = xb;

    cast_f32_bf16<<<dim3(nx4 / 256), blk, 0, stream>>>(x, xb, nx4);
    cast_f32_bf16<<<dim3(nw4 / 256), blk, 0, stream>>>(wq, wb3, nw4);
    cast_f32_bf16<<<dim3(nw4 / 256), blk, 0, stream>>>(wk, wb3 + nw, nw4);
    cast_f32_bf16<<<dim3(nw4 / 256), blk, 0, stream>>>(wv, wb3 + 2 * nw, nw4);

    gemm_qkv<<<dim3(M_ / 128, 48), blk, 0, stream>>>(xb, wb3, qb, kb, vb, M_, D_);

    flash_attn<<<dim3(8, B_ * H_), blk, 0, stream>>>(qb, kb, vb, yb, fc, fs);

    cast_f32_bf16<<<dim3(nw4 / 256), blk, 0, stream>>>(wo, wb3, nw4);
    gemm_bt<float><<<gg, blk, 0, stream>>>(yb, wb3, out, M_, D_, D_);
  } else {
    // ---- Path B: serial 3-gemm fallback (75.5 MB ws) ----
    bf16_t* ws = (bf16_t*)d_ws;
    bf16_t* wb = ws;
    bf16_t* xb = ws + nw;
    bf16_t* qb = xb + nx;
    bf16_t* kb = qb + nx;
    bf16_t* vb = kb + nx;
    bf16_t* yb = xb;

    cast_f32_bf16<<<dim3(nx4 / 256), blk, 0, stream>>>(x, xb, nx4);
    cast_f32_bf16<<<dim3(nw4 / 256), blk, 0, stream>>>(wq, wb, nw4);
    gemm_bt<bf16_t><<<gg, blk, 0, stream>>>(xb, wb, qb, M_, D_, D_);
    cast_f32_bf16<<<dim3(nw4 / 256), blk, 0, stream>>>(wk, wb, nw4);
    gemm_bt<bf16_t><<<gg, blk, 0, stream>>>(xb, wb, kb, M_, D_, D_);
    cast_f32_bf16<<<dim3(nw4 / 256), blk, 0, stream>>>(wv, wb, nw4);
    gemm_bt<bf16_t><<<gg, blk, 0, stream>>>(xb, wb, vb, M_, D_, D_);

    flash_attn<<<dim3(8, B_ * H_), blk, 0, stream>>>(qb, kb, vb, yb, fc, fs);

    cast_f32_bf16<<<dim3(nw4 / 256), blk, 0, stream>>>(wo, wb, nw4);
    gemm_bt<float><<<gg, blk, 0, stream>>>(yb, wb, out, M_, D_, D_);
  }
}